// Round 1
// baseline (1332.684 us; speedup 1.0000x reference)
//
#include <hip/hip_runtime.h>
#include <math.h>

#define BATCH 2048
#define NPOS 4
#define NNEG 128
#define DIM 1024
#define NS (NNEG + 1)   // 129 samples per row
#define EPSV 1e-6f

__device__ __forceinline__ float dot4(float4 a, float4 b) {
    return a.x * b.x + a.y * b.y + a.z * b.z + a.w * b.w;
}

// One block per batch row b. 256 threads = 4 waves; wave w handles samples
// s = w, w+4, ... Each lane loads 4x float4 covering D=1024 (64 lanes * 16
// floats). Anchor kept in registers (same copy in every wave).
__global__ __launch_bounds__(256) void contrastive_row_kernel(
    const float* __restrict__ anchor,     // [B, 1, D]
    const float* __restrict__ positives,  // [B, P, D]
    const float* __restrict__ negatives,  // [B, N, D]
    float* __restrict__ partial)          // [B] per-row loss
{
    const int b    = blockIdx.x;
    const int tid  = threadIdx.x;
    const int lane = tid & 63;
    const int wave = tid >> 6;

    __shared__ float s_sim[NS];
    __shared__ float s_na;
    __shared__ float s_red[8];

    const float4* a_ptr = (const float4*)(anchor + (size_t)b * DIM);
    const float4 a0 = a_ptr[lane];
    const float4 a1 = a_ptr[64 + lane];
    const float4 a2 = a_ptr[128 + lane];
    const float4 a3 = a_ptr[192 + lane];

    // ||a|| — wave 0 only (all waves hold identical anchor fragments)
    if (wave == 0) {
        float s = dot4(a0, a0) + dot4(a1, a1) + dot4(a2, a2) + dot4(a3, a3);
        #pragma unroll
        for (int off = 32; off; off >>= 1) s += __shfl_xor(s, off);
        if (lane == 0) s_na = fmaxf(sqrtf(s), EPSV);
    }
    __syncthreads();
    const float na = s_na;

    const float4* pos_last = (const float4*)(positives + ((size_t)b * NPOS + (NPOS - 1)) * DIM);
    const float4* negs     = (const float4*)(negatives + (size_t)b * NNEG * DIM);

    for (int s = wave; s < NS; s += 4) {
        const float4* row = (s == 0) ? pos_last : (negs + (size_t)(s - 1) * (DIM / 4));
        float4 v0 = row[lane];
        float4 v1 = row[64 + lane];
        float4 v2 = row[128 + lane];
        float4 v3 = row[192 + lane];
        float dotv = dot4(a0, v0) + dot4(a1, v1) + dot4(a2, v2) + dot4(a3, v3);
        float nrm  = dot4(v0, v0) + dot4(v1, v1) + dot4(v2, v2) + dot4(v3, v3);
        #pragma unroll
        for (int off = 32; off; off >>= 1) {
            dotv += __shfl_xor(dotv, off);
            nrm  += __shfl_xor(nrm,  off);
        }
        if (lane == 0) {
            float ns = fmaxf(sqrtf(nrm), EPSV);
            s_sim[s] = dotv / (na * ns);
        }
    }
    __syncthreads();

    // log-softmax over s_sim[0..NS-1]; loss_b = -(sim[0] - m - log(sum_exp))
    float v = (tid < NS) ? s_sim[tid] : -INFINITY;
    float m = v;
    #pragma unroll
    for (int off = 32; off; off >>= 1) m = fmaxf(m, __shfl_xor(m, off));
    if (lane == 0) s_red[wave] = m;
    __syncthreads();
    if (tid == 0) {
        s_red[4] = fmaxf(fmaxf(s_red[0], s_red[1]), fmaxf(s_red[2], s_red[3]));
    }
    __syncthreads();
    m = s_red[4];

    float e = (tid < NS) ? expf(v - m) : 0.0f;
    #pragma unroll
    for (int off = 32; off; off >>= 1) e += __shfl_xor(e, off);
    if (lane == 0) s_red[wave] = e;
    __syncthreads();
    if (tid == 0) {
        float sum = s_red[0] + s_red[1] + s_red[2] + s_red[3];
        partial[b] = -(s_sim[0] - m - logf(sum));
    }
}

__global__ __launch_bounds__(256) void reduce_mean_kernel(
    const float* __restrict__ partial, float* __restrict__ out)
{
    __shared__ float s_red[4];
    const int tid  = threadIdx.x;
    const int lane = tid & 63;
    const int wave = tid >> 6;
    float s = 0.0f;
    for (int i = tid; i < BATCH; i += 256) s += partial[i];
    #pragma unroll
    for (int off = 32; off; off >>= 1) s += __shfl_xor(s, off);
    if (lane == 0) s_red[wave] = s;
    __syncthreads();
    if (tid == 0) {
        out[0] = (s_red[0] + s_red[1] + s_red[2] + s_red[3]) / (float)BATCH;
    }
}

extern "C" void kernel_launch(void* const* d_in, const int* in_sizes, int n_in,
                              void* d_out, int out_size, void* d_ws, size_t ws_size,
                              hipStream_t stream) {
    const float* anchor    = (const float*)d_in[0];
    const float* positives = (const float*)d_in[1];
    const float* negatives = (const float*)d_in[2];
    float* out     = (float*)d_out;
    float* partial = (float*)d_ws;   // BATCH floats = 8 KB scratch

    contrastive_row_kernel<<<BATCH, 256, 0, stream>>>(anchor, positives, negatives, partial);
    reduce_mean_kernel<<<1, 256, 0, stream>>>(partial, out);
}